// Round 2
// baseline (1113.826 us; speedup 1.0000x reference)
//
#include <hip/hip_runtime.h>

typedef __attribute__((ext_vector_type(8))) short short8;
typedef __attribute__((ext_vector_type(4))) float f32x4;
typedef __attribute__((ext_vector_type(4))) unsigned short u16x4;
typedef __attribute__((ext_vector_type(8))) unsigned short u16x8;

typedef __attribute__((address_space(3))) void lds_void;
typedef __attribute__((address_space(1))) void g_void;

#define GL16(g, l) __builtin_amdgcn_global_load_lds((g_void*)(g), (lds_void*)(l), 16, 0, 0)

__device__ inline float b2f(unsigned short u) {
  union { unsigned u; float f; } v; v.u = ((unsigned)u) << 16; return v.f;
}
__device__ inline unsigned short f2b(float f) {
  union { float f; unsigned u; } v; v.f = f;
  unsigned r = v.u + 0x7FFFu + ((v.u >> 16) & 1u);
  return (unsigned short)(r >> 16);
}
__device__ inline unsigned short cvtb(float v) { return f2b(v); }
__device__ inline unsigned short cvtb(unsigned short v) { return v; }

// ---------- fp32 -> bf16 convert (vectorized) ----------
__global__ __launch_bounds__(256) void conv_f32_bf16(const float* __restrict__ in,
                                                     unsigned short* __restrict__ out, long n) {
  long i = ((long)blockIdx.x * 256 + threadIdx.x) * 4;
  if (i >= n) return;
  f32x4 v = *(const f32x4*)(in + i);
  u16x4 o;
  o[0] = f2b(v[0]); o[1] = f2b(v[1]); o[2] = f2b(v[2]); o[3] = f2b(v[3]);
  *(u16x4*)(out + i) = o;
}

// ---------- transpose (R x C) -> bf16 (C x R) ----------
template <typename TIN>
__global__ __launch_bounds__(256) void transpose_bf16(const TIN* __restrict__ in,
                                                      unsigned short* __restrict__ out,
                                                      int R, int C) {
  __shared__ unsigned short tile[32][33];
  int c0 = blockIdx.x * 32, r0 = blockIdx.y * 32;
  int tx = threadIdx.x & 31, ty = threadIdx.x >> 5;
#pragma unroll
  for (int i = ty; i < 32; i += 8)
    tile[i][tx] = cvtb(in[(long)(r0 + i) * C + c0 + tx]);
  __syncthreads();
#pragma unroll
  for (int i = ty; i < 32; i += 8)
    out[(long)(c0 + i) * R + r0 + tx] = tile[tx][i];
}

// ---------- RoPE in-place on bf16 (row-major rows x H*128), scale folded ----------
__global__ __launch_bounds__(256) void rope_kernel(unsigned short* __restrict__ QK,
                                                   const float* __restrict__ cosp,
                                                   const float* __restrict__ sinp,
                                                   int hshift, int smask, float scale, int total) {
  int idx = blockIdx.x * 256 + threadIdx.x;
  if (idx >= total) return;
  int seg = idx & 15;
  int rh = idx >> 4;                 // row*H + h
  int s = (rh >> hshift) & smask;    // row % S  (S power of 2)
  int d0 = seg << 3;
  unsigned short* p = QK + (long)rh * 128 + d0;
  u16x8 v = *(const u16x8*)p;
  u16x8 o;
  int ib = d0 >> 1;
#pragma unroll
  for (int q = 0; q < 4; q++) {
    float c = cosp[s * 64 + ib + q];
    float sn = sinp[s * 64 + ib + q];
    float e = b2f(v[2 * q]), od = b2f(v[2 * q + 1]);
    o[2 * q]     = f2b((e * c - od * sn) * scale);
    o[2 * q + 1] = f2b((e * sn + od * c) * scale);
  }
  *(u16x8*)p = o;
}

// ---------- bf16 GEMM: C(MxN) = A(MxK) * Bt(NxK)^T ; m97 structure ----------
template <bool OUT_BF16>
__global__ __launch_bounds__(256) void gemm_bt(const unsigned short* __restrict__ A,
                                               const unsigned short* __restrict__ Bt,
                                               void* __restrict__ C, int M, int N, int K) {
  __shared__ unsigned short As[128 * 32];
  __shared__ unsigned short Bs[128 * 32];
  const int tid = threadIdx.x;
  const int wave = tid >> 6, lane = tid & 63;
  const int lrow = lane & 15, kgrp = lane >> 4;
  const int nb = N >> 7;
  const int bm = blockIdx.x / nb, bn = blockIdx.x % nb;
  const int wr = wave >> 1, wc = wave & 1;

  f32x4 acc[4][4];
#pragma unroll
  for (int m = 0; m < 4; m++)
#pragma unroll
    for (int n = 0; n < 4; n++) acc[m][n] = (f32x4){0.f, 0.f, 0.f, 0.f};

  const char* ga = (const char*)(A + (long)(bm * 128 + (tid >> 2)) * K) + (tid & 3) * 16;
  const char* gb = (const char*)(Bt + (long)(bn * 128 + (tid >> 2)) * K) + (tid & 3) * 16;
  const long rowstep = (long)64 * K * 2;
  char* lA = (char*)As + wave * 1024;
  char* lB = (char*)Bs + wave * 1024;

  for (int k0 = 0; k0 < K; k0 += 32) {
    __syncthreads();
    GL16(ga + (long)k0 * 2, lA);
    GL16(ga + (long)k0 * 2 + rowstep, lA + 4096);
    GL16(gb + (long)k0 * 2, lB);
    GL16(gb + (long)k0 * 2 + rowstep, lB + 4096);
    __syncthreads();
    short8 af[4], bfv[4];
#pragma unroll
    for (int m = 0; m < 4; m++)
      af[m] = *(const short8*)(As + (wr * 64 + m * 16 + lrow) * 32 + kgrp * 8);
#pragma unroll
    for (int n = 0; n < 4; n++)
      bfv[n] = *(const short8*)(Bs + (wc * 64 + n * 16 + lrow) * 32 + kgrp * 8);
#pragma unroll
    for (int m = 0; m < 4; m++)
#pragma unroll
      for (int n = 0; n < 4; n++)
        acc[m][n] = __builtin_amdgcn_mfma_f32_16x16x32_bf16(af[m], bfv[n], acc[m][n], 0, 0, 0);
  }

  const long crow0 = (long)bm * 128 + wr * 64 + kgrp * 4;
  const int ccol0 = bn * 128 + wc * 64 + lrow;
#pragma unroll
  for (int m = 0; m < 4; m++)
#pragma unroll
    for (int n = 0; n < 4; n++)
#pragma unroll
      for (int r = 0; r < 4; r++) {
        long row = crow0 + m * 16 + r;
        int col = ccol0 + n * 16;
        if (OUT_BF16)
          ((unsigned short*)C)[row * N + col] = f2b(acc[m][n][r]);
        else
          ((float*)C)[row * N + col] = acc[m][n][r];
      }
}

// ---------- flash attention, causal, GQA(4:1) ----------
// Q: (B*S) x 4096 bf16 (scale pre-folded), K: (B*S) x 1024 bf16,
// Vt: 1024 x (B*S) bf16 (transposed V), O: (B*S) x 4096 bf16
__global__ __launch_bounds__(256) void attn_kernel(const unsigned short* __restrict__ Q,
                                                   const unsigned short* __restrict__ K,
                                                   const unsigned short* __restrict__ Vt,
                                                   unsigned short* __restrict__ O,
                                                   int S, int BS) {
  __shared__ unsigned short Ks[64 * 128];   // [kv][d]
  __shared__ unsigned short Vs[128 * 64];   // [d][kv]
  __shared__ unsigned short Ps[4][16 * 72]; // per-wave [q][kv], pad 72
  const int tid = threadIdx.x, wave = tid >> 6, lane = tid & 63;
  const int lrow = lane & 15, kgrp = lane >> 4;
  const int nqt = S >> 6;
  int bid = blockIdx.x;
  const int qt = bid % nqt; bid /= nqt;
  const int h = bid & 31;
  const int b = bid >> 5;
  const int kh = h >> 2;
  const long rowbase = (long)b * S;
  const int qbase = qt * 64;
  const int q0 = qbase + wave * 16;

  short8 qf[4];
  {
    const unsigned short* qp = Q + (rowbase + q0 + lrow) * 4096 + h * 128 + kgrp * 8;
#pragma unroll
    for (int dc = 0; dc < 4; dc++) qf[dc] = *(const short8*)(qp + dc * 32);
  }
  f32x4 oacc[8];
#pragma unroll
  for (int dt = 0; dt < 8; dt++) oacc[dt] = (f32x4){0.f, 0.f, 0.f, 0.f};
  float mrun[4] = {-1e30f, -1e30f, -1e30f, -1e30f};
  float lrun[4] = {0.f, 0.f, 0.f, 0.f};

  const char* kg = (const char*)(K + rowbase * 1024 + kh * 128) + (tid >> 4) * 2048 + (tid & 15) * 16;
  const char* vg = (const char*)(Vt + (long)(kh * 128 + (tid >> 3)) * BS + rowbase) + (tid & 7) * 16;
  char* lK = (char*)Ks + wave * 1024;
  char* lV = (char*)Vs + wave * 1024;

  const int kv_end = qbase + 64;
  for (int kv0 = 0; kv0 < kv_end; kv0 += 64) {
    __syncthreads();
#pragma unroll
    for (int p = 0; p < 4; p++)
      GL16(kg + (long)(kv0 + p * 16) * 2048, lK + p * 4096);
#pragma unroll
    for (int p = 0; p < 4; p++)
      GL16(vg + (long)kv0 * 2 + (long)p * 32 * BS * 2, lV + p * 4096);
    __syncthreads();

    f32x4 sc[4];
#pragma unroll
    for (int n = 0; n < 4; n++) {
      f32x4 s = (f32x4){0.f, 0.f, 0.f, 0.f};
#pragma unroll
      for (int dc = 0; dc < 4; dc++) {
        short8 kf = *(const short8*)(Ks + (n * 16 + lrow) * 128 + dc * 32 + kgrp * 8);
        s = __builtin_amdgcn_mfma_f32_16x16x32_bf16(qf[dc], kf, s, 0, 0, 0);
      }
      sc[n] = s;
    }
#pragma unroll
    for (int r = 0; r < 4; r++) {
      const int qg = q0 + kgrp * 4 + r;
#pragma unroll
      for (int n = 0; n < 4; n++) {
        int kgi = kv0 + n * 16 + lrow;
        if (kgi > qg) sc[n][r] = -1e30f;
      }
      float mx = fmaxf(fmaxf(sc[0][r], sc[1][r]), fmaxf(sc[2][r], sc[3][r]));
#pragma unroll
      for (int d = 1; d < 16; d <<= 1) mx = fmaxf(mx, __shfl_xor(mx, d, 64));
      float mnew = fmaxf(mrun[r], mx);
      float corr = __expf(mrun[r] - mnew);
      mrun[r] = mnew;
      float psum = 0.f;
#pragma unroll
      for (int n = 0; n < 4; n++) {
        float pv = __expf(sc[n][r] - mnew);
        psum += pv;
        Ps[wave][(kgrp * 4 + r) * 72 + n * 16 + lrow] = f2b(pv);
      }
      lrun[r] = lrun[r] * corr + psum;
#pragma unroll
      for (int dt = 0; dt < 8; dt++) oacc[dt][r] *= corr;
    }
    asm volatile("s_waitcnt lgkmcnt(0)" ::: "memory");
#pragma unroll
    for (int kc = 0; kc < 2; kc++) {
      short8 pa = *(const short8*)(&Ps[wave][lrow * 72 + kc * 32 + kgrp * 8]);
#pragma unroll
      for (int dt = 0; dt < 8; dt++) {
        short8 vb = *(const short8*)(Vs + (dt * 16 + lrow) * 64 + kc * 32 + kgrp * 8);
        oacc[dt] = __builtin_amdgcn_mfma_f32_16x16x32_bf16(pa, vb, oacc[dt], 0, 0, 0);
      }
    }
  }

  float inv[4];
#pragma unroll
  for (int r = 0; r < 4; r++) {
    float l = lrun[r];
#pragma unroll
    for (int d = 1; d < 16; d <<= 1) l += __shfl_xor(l, d, 64);
    inv[r] = 1.f / l;
  }
  unsigned short* op = O + (rowbase + q0 + kgrp * 4) * 4096 + h * 128 + lrow;
#pragma unroll
  for (int dt = 0; dt < 8; dt++)
#pragma unroll
    for (int r = 0; r < 4; r++)
      op[(long)r * 4096 + dt * 16] = f2b(oacc[dt][r] * inv[r]);
}

extern "C" void kernel_launch(void* const* d_in, const int* in_sizes, int n_in,
                              void* d_out, int out_size, void* d_ws, size_t ws_size,
                              hipStream_t stream) {
  const float* x = (const float*)d_in[0];
  const float* cosp = (const float*)d_in[1];
  const float* sinp = (const float*)d_in[2];
  // d_in[3] = mask (causal 0/-1e9) — applied analytically
  const float* Wq = (const float*)d_in[4];
  const float* Wk = (const float*)d_in[5];
  const float* Wv = (const float*)d_in[6];
  const float* Wo = (const float*)d_in[7];
  const int S = 2048;
  const long M = 4096; // B*S

  if (ws_size < 176160768ULL) return; // need 168 MiB scratch

  char* ws = (char*)d_ws;
  unsigned short* xb  = (unsigned short*)(ws);                 // 32 MiB  (aliased as AO later)
  unsigned short* Wqt = (unsigned short*)(ws + 33554432);      // 32 MiB
  unsigned short* Wkt = (unsigned short*)(ws + 67108864);      // 8 MiB
  unsigned short* Wvt = (unsigned short*)(ws + 75497472);      // 8 MiB
  unsigned short* Wot = (unsigned short*)(ws + 83886080);      // 32 MiB
  unsigned short* Qb  = (unsigned short*)(ws + 117440512);     // 32 MiB
  unsigned short* Kb  = (unsigned short*)(ws + 150994944);     // 8 MiB
  unsigned short* Vb  = (unsigned short*)(ws + 159383552);     // 8 MiB
  unsigned short* Vtg = (unsigned short*)(ws + 167772160);     // 8 MiB
  unsigned short* AO  = xb; // xb dead after QKV GEMMs

  conv_f32_bf16<<<16384, 256, 0, stream>>>(x, xb, M * 4096);
  transpose_bf16<float><<<dim3(128, 128), 256, 0, stream>>>(Wq, Wqt, 4096, 4096);
  transpose_bf16<float><<<dim3(32, 128), 256, 0, stream>>>(Wk, Wkt, 4096, 1024);
  transpose_bf16<float><<<dim3(32, 128), 256, 0, stream>>>(Wv, Wvt, 4096, 1024);
  transpose_bf16<float><<<dim3(128, 128), 256, 0, stream>>>(Wo, Wot, 4096, 4096);

  gemm_bt<true><<<1024, 256, 0, stream>>>(xb, Wqt, Qb, 4096, 4096, 4096);
  gemm_bt<true><<<256, 256, 0, stream>>>(xb, Wkt, Kb, 4096, 1024, 4096);
  gemm_bt<true><<<256, 256, 0, stream>>>(xb, Wvt, Vb, 4096, 1024, 4096);
  transpose_bf16<unsigned short><<<dim3(32, 128), 256, 0, stream>>>(Vb, Vtg, 4096, 1024);

  const float qscale = 0.08838834764831845f; // 1/sqrt(128)
  rope_kernel<<<8192, 256, 0, stream>>>(Qb, cosp, sinp, 5, S - 1, qscale, 4096 * 32 * 16);
  rope_kernel<<<2048, 256, 0, stream>>>(Kb, cosp, sinp, 3, S - 1, 1.0f, 4096 * 8 * 16);

  attn_kernel<<<2048, 256, 0, stream>>>(Qb, Kb, Vtg, AO, S, 4096);

  gemm_bt<false><<<1024, 256, 0, stream>>>(AO, Wot, d_out, 4096, 4096, 4096);
}

// Round 5
// 867.318 us; speedup vs baseline: 1.2842x; 1.2842x over previous
//
#include <hip/hip_runtime.h>

typedef __attribute__((ext_vector_type(8))) short short8;
typedef __attribute__((ext_vector_type(4))) float f32x4;
typedef __attribute__((ext_vector_type(4))) unsigned short u16x4;
typedef __attribute__((ext_vector_type(8))) unsigned short u16x8;

typedef __attribute__((address_space(3))) void lds_void;
typedef __attribute__((address_space(1))) void g_void;

#define GL16(g, l) __builtin_amdgcn_global_load_lds((g_void*)(g), (lds_void*)(l), 16, 0, 0)
#define EXP2F(x) __builtin_exp2f(x)

__device__ inline float b2f(unsigned short u) {
  union { unsigned u; float f; } v; v.u = ((unsigned)u) << 16; return v.f;
}
__device__ inline unsigned short f2b(float f) {
  union { float f; unsigned u; } v; v.f = f;
  unsigned r = v.u + 0x7FFFu + ((v.u >> 16) & 1u);
  return (unsigned short)(r >> 16);
}
__device__ inline unsigned short cvtb(float v) { return f2b(v); }
__device__ inline unsigned short cvtb(unsigned short v) { return v; }

// ---------- fp32 -> bf16 convert (vectorized) ----------
__global__ __launch_bounds__(256) void conv_f32_bf16(const float* __restrict__ in,
                                                     unsigned short* __restrict__ out, long n) {
  long i = ((long)blockIdx.x * 256 + threadIdx.x) * 4;
  if (i >= n) return;
  f32x4 v = *(const f32x4*)(in + i);
  u16x4 o;
  o[0] = f2b(v[0]); o[1] = f2b(v[1]); o[2] = f2b(v[2]); o[3] = f2b(v[3]);
  *(u16x4*)(out + i) = o;
}

// ---------- transpose (R x C block of ldin-stride matrix) -> bf16 (C x R) ----------
template <typename TIN>
__global__ __launch_bounds__(256) void transpose_bf16(const TIN* __restrict__ in,
                                                      unsigned short* __restrict__ out,
                                                      int R, int C, int ldin) {
  __shared__ unsigned short tile[32][33];
  int c0 = blockIdx.x * 32, r0 = blockIdx.y * 32;
  int tx = threadIdx.x & 31, ty = threadIdx.x >> 5;
#pragma unroll
  for (int i = ty; i < 32; i += 8)
    tile[i][tx] = cvtb(in[(long)(r0 + i) * ldin + c0 + tx]);
  __syncthreads();
#pragma unroll
  for (int i = ty; i < 32; i += 8)
    out[(long)(c0 + i) * R + r0 + tx] = tile[tx][i];
}

// ---------- RoPE in-place on bf16 (rows of ld elems, H heads x 128), scale folded ----------
__global__ __launch_bounds__(256) void rope_kernel(unsigned short* __restrict__ QK,
                                                   const float* __restrict__ cosp,
                                                   const float* __restrict__ sinp,
                                                   int ld, int hshift, int smask,
                                                   float scale, int total) {
  int idx = blockIdx.x * 256 + threadIdx.x;
  if (idx >= total) return;
  int seg = idx & 15;
  int hh = (idx >> 4) & ((1 << hshift) - 1);
  int row = idx >> (4 + hshift);
  int s = row & smask;
  int d0 = seg << 3;
  unsigned short* p = QK + (long)row * ld + hh * 128 + d0;
  u16x8 v = *(const u16x8*)p;
  u16x8 o;
  int ib = d0 >> 1;
#pragma unroll
  for (int q = 0; q < 4; q++) {
    float c = cosp[s * 64 + ib + q];
    float sn = sinp[s * 64 + ib + q];
    float e = b2f(v[2 * q]), od = b2f(v[2 * q + 1]);
    o[2 * q]     = f2b((e * c - od * sn) * scale);
    o[2 * q + 1] = f2b((e * sn + od * c) * scale);
  }
  *(u16x8*)p = o;
}

// ---------- bf16 GEMM: C(MxN) = A(MxK) * Bt(NxK)^T ; m97 structure ----------
template <bool OUT_BF16>
__global__ __launch_bounds__(256) void gemm_bt(const unsigned short* __restrict__ A,
                                               const unsigned short* __restrict__ Bt,
                                               void* __restrict__ C, int M, int N, int K) {
  __shared__ unsigned short As[128 * 32];
  __shared__ unsigned short Bs[128 * 32];
  const int tid = threadIdx.x;
  const int wave = tid >> 6, lane = tid & 63;
  const int lrow = lane & 15, kgrp = lane >> 4;
  const int nb = N >> 7;
  const int bm = blockIdx.x / nb, bn = blockIdx.x % nb;
  const int wr = wave >> 1, wc = wave & 1;

  f32x4 acc[4][4];
#pragma unroll
  for (int m = 0; m < 4; m++)
#pragma unroll
    for (int n = 0; n < 4; n++) acc[m][n] = (f32x4){0.f, 0.f, 0.f, 0.f};

  const char* ga = (const char*)(A + (long)(bm * 128 + (tid >> 2)) * K) + (tid & 3) * 16;
  const char* gb = (const char*)(Bt + (long)(bn * 128 + (tid >> 2)) * K) + (tid & 3) * 16;
  const long rowstep = (long)64 * K * 2;
  char* lA = (char*)As + wave * 1024;
  char* lB = (char*)Bs + wave * 1024;

  for (int k0 = 0; k0 < K; k0 += 32) {
    __syncthreads();
    GL16(ga + (long)k0 * 2, lA);
    GL16(ga + (long)k0 * 2 + rowstep, lA + 4096);
    GL16(gb + (long)k0 * 2, lB);
    GL16(gb + (long)k0 * 2 + rowstep, lB + 4096);
    __syncthreads();
    short8 af[4], bfv[4];
#pragma unroll
    for (int m = 0; m < 4; m++)
      af[m] = *(const short8*)(As + (wr * 64 + m * 16 + lrow) * 32 + kgrp * 8);
#pragma unroll
    for (int n = 0; n < 4; n++)
      bfv[n] = *(const short8*)(Bs + (wc * 64 + n * 16 + lrow) * 32 + kgrp * 8);
#pragma unroll
    for (int m = 0; m < 4; m++)
#pragma unroll
      for (int n = 0; n < 4; n++)
        acc[m][n] = __builtin_amdgcn_mfma_f32_16x16x32_bf16(af[m], bfv[n], acc[m][n], 0, 0, 0);
  }

  const long crow0 = (long)bm * 128 + wr * 64 + kgrp * 4;
  const int ccol0 = bn * 128 + wc * 64 + lrow;
#pragma unroll
  for (int m = 0; m < 4; m++)
#pragma unroll
    for (int n = 0; n < 4; n++)
#pragma unroll
      for (int r = 0; r < 4; r++) {
        long row = crow0 + m * 16 + r;
        int col = ccol0 + n * 16;
        if (OUT_BF16)
          ((unsigned short*)C)[row * N + col] = f2b(acc[m][n][r]);
        else
          ((float*)C)[row * N + col] = acc[m][n][r];
      }
}

// ---------- flash attention, causal, GQA(4:1), XOR-swizzled LDS ----------
// QKV: (B*S) x 6144 bf16 (Q cols 0..4095 scale*log2e-folded, K cols 4096..5119),
// Vt: 1024 x (B*S) bf16 (transposed V), O: (B*S) x 4096 bf16
__global__ __launch_bounds__(256) void attn_kernel(const unsigned short* __restrict__ QKV,
                                                   const unsigned short* __restrict__ Vt,
                                                   unsigned short* __restrict__ O,
                                                   int S, int BS) {
  __shared__ unsigned short Ks[64 * 128];   // [kv][d], chunk^=(kv&7)
  __shared__ unsigned short Vs[128 * 64];   // [d][kv], chunk^=(d&7)
  __shared__ unsigned short Ps[4][16 * 68]; // per-wave [q][kv], pad 68
  const int tid = threadIdx.x, wave = tid >> 6, lane = tid & 63;
  const int lrow = lane & 15, kgrp = lane >> 4;
  const int nqt = S >> 6;
  int bid = blockIdx.x;
  const int qt = bid % nqt; bid /= nqt;
  const int h = bid & 31;
  const int b = bid >> 5;
  const int kh = h >> 2;
  const long rowbase = (long)b * S;
  const int qbase = qt * 64;
  const int q0 = qbase + wave * 16;

  short8 qf[4];
  {
    const unsigned short* qp = QKV + (rowbase + q0 + lrow) * 6144 + h * 128 + kgrp * 8;
#pragma unroll
    for (int dc = 0; dc < 4; dc++) qf[dc] = *(const short8*)(qp + dc * 32);
  }
  f32x4 oacc[8];
#pragma unroll
  for (int dt = 0; dt < 8; dt++) oacc[dt] = (f32x4){0.f, 0.f, 0.f, 0.f};
  float mrun[4] = {-1e30f, -1e30f, -1e30f, -1e30f};
  float lrun[4] = {0.f, 0.f, 0.f, 0.f};

  // K staging: row = tid>>4 (of 16/pass), chunk (16B) = tid&15, src chunk pre-swizzled
  const char* kg = (const char*)(QKV + rowbase * 6144 + 4096 + kh * 128)
                   + (tid >> 4) * 12288 + (((tid & 15) ^ ((tid >> 4) & 7)) * 16);
  // V staging: d-row = tid>>3 (of 32/pass), chunk = tid&7, pre-swizzled
  const char* vg = (const char*)(Vt + (long)(kh * 128 + (tid >> 3)) * BS + rowbase)
                   + (((tid & 7) ^ ((tid >> 3) & 7)) * 16);
  char* lK = (char*)Ks + wave * 1024;
  char* lV = (char*)Vs + wave * 1024;

  const int kv_end = qbase + 64;
  for (int kv0 = 0; kv0 < kv_end; kv0 += 64) {
    __syncthreads();
#pragma unroll
    for (int p = 0; p < 4; p++)
      GL16(kg + (long)(kv0 + p * 16) * 12288, lK + p * 4096);
#pragma unroll
    for (int p = 0; p < 4; p++)
      GL16(vg + (long)kv0 * 2 + (long)p * 32 * BS * 2, lV + p * 4096);
    __syncthreads();

    f32x4 sc[4];
#pragma unroll
    for (int n = 0; n < 4; n++) {
      f32x4 s = (f32x4){0.f, 0.f, 0.f, 0.f};
#pragma unroll
      for (int dc = 0; dc < 4; dc++) {
        short8 kf = *(const short8*)(Ks + (n * 16 + lrow) * 128 + (((dc * 4 + kgrp) ^ (lrow & 7)) << 3));
        s = __builtin_amdgcn_mfma_f32_16x16x32_bf16(qf[dc], kf, s, 0, 0, 0);
      }
      sc[n] = s;
    }
#pragma unroll
    for (int r = 0; r < 4; r++) {
      const int qg = q0 + kgrp * 4 + r;
#pragma unroll
      for (int n = 0; n < 4; n++) {
        int kgi = kv0 + n * 16 + lrow;
        if (kgi > qg) sc[n][r] = -1e30f;
      }
      float mx = fmaxf(fmaxf(sc[0][r], sc[1][r]), fmaxf(sc[2][r], sc[3][r]));
#pragma unroll
      for (int d = 1; d < 16; d <<= 1) mx = fmaxf(mx, __shfl_xor(mx, d, 64));
      float mnew = fmaxf(mrun[r], mx);
      float corr = EXP2F(mrun[r] - mnew);
      mrun[r] = mnew;
      float psum = 0.f;
#pragma unroll
      for (int n = 0; n < 4; n++) {
        float pv = EXP2F(sc[n][r] - mnew);
        psum += pv;
        Ps[wave][(kgrp * 4 + r) * 68 + n * 16 + lrow] = f2b(pv);
      }
      lrun[r] = lrun[r] * corr + psum;
#pragma unroll
      for (int dt = 0; dt < 8; dt++) oacc[dt][r] *= corr;
    }
    asm volatile("s_waitcnt lgkmcnt(0)" ::: "memory");
#pragma unroll
    for (int kc = 0; kc < 2; kc++) {
      short8 pa = *(const short8*)(&Ps[wave][lrow * 68 + kc * 32 + kgrp * 8]);
#pragma unroll
      for (int dt = 0; dt < 8; dt++) {
        short8 vb = *(const short8*)(Vs + (dt * 16 + lrow) * 64 + (((kc * 4 + kgrp) ^ (lrow & 7)) << 3));
        oacc[dt] = __builtin_amdgcn_mfma_f32_16x16x32_bf16(pa, vb, oacc[dt], 0, 0, 0);
      }
    }
  }

  float inv[4];
#pragma unroll
  for (int r = 0; r < 4; r++) {
    float l = lrun[r];
#pragma unroll
    for (int d = 1; d < 16; d <<= 1) l += __shfl_xor(l, d, 64);
    inv[r] = 1.f / l;
  }
  unsigned short* op = O + (rowbase + q0 + kgrp * 4) * 4096 + h * 128 + lrow;
#pragma unroll
  for (int dt = 0; dt < 8; dt++)
#pragma unroll
    for (int r = 0; r < 4; r++)
      op[(long)r * 4096 + dt * 16] = f2b(oacc[dt][r] * inv[r]);
}

extern "C" void kernel_launch(void* const* d_in, const int* in_sizes, int n_in,
                              void* d_out, int out_size, void* d_ws, size_t ws_size,
                              hipStream_t stream) {
  const float* x = (const float*)d_in[0];
  const float* cosp = (const float*)d_in[1];
  const float* sinp = (const float*)d_in[2];
  // d_in[3] = mask (causal 0/-1e9) -- applied analytically
  const float* Wq = (const float*)d_in[4];
  const float* Wk = (const float*)d_in[5];
  const float* Wv = (const float*)d_in[6];
  const float* Wo = (const float*)d_in[7];
  const int S = 2048;
  const long M = 4096; // B*S

  if (ws_size < 176160768ULL) return; // need 168 MiB scratch

  char* ws = (char*)d_ws;
  unsigned short* xb   = (unsigned short*)(ws);               // 32 MiB (aliased as AO later)
  unsigned short* Wqt  = (unsigned short*)(ws + 33554432);    // 32 MiB (Wqt,Wkt,Wvt contiguous: [6144][4096])
  unsigned short* Wkt  = (unsigned short*)(ws + 67108864);    //  8 MiB
  unsigned short* Wvt  = (unsigned short*)(ws + 75497472);    //  8 MiB
  unsigned short* Wot  = (unsigned short*)(ws + 83886080);    // 32 MiB
  unsigned short* QKVb = (unsigned short*)(ws + 117440512);   // 48 MiB [4096][6144]
  unsigned short* Vtg  = (unsigned short*)(ws + 167772160);   //  8 MiB [1024][4096]
  unsigned short* AO   = xb; // xb dead after QKV GEMM

  conv_f32_bf16<<<16384, 256, 0, stream>>>(x, xb, M * 4096);
  transpose_bf16<float><<<dim3(128, 128), 256, 0, stream>>>(Wq, Wqt, 4096, 4096, 4096);
  transpose_bf16<float><<<dim3(32, 128), 256, 0, stream>>>(Wk, Wkt, 4096, 1024, 1024);
  transpose_bf16<float><<<dim3(32, 128), 256, 0, stream>>>(Wv, Wvt, 4096, 1024, 1024);
  transpose_bf16<float><<<dim3(128, 128), 256, 0, stream>>>(Wo, Wot, 4096, 4096, 4096);

  // fused QKV projection: Bt = [Wqt|Wkt|Wvt] (6144 x 4096), C = QKVb (4096 x 6144)
  gemm_bt<true><<<1536, 256, 0, stream>>>(xb, Wqt, QKVb, 4096, 6144, 4096);
  // V^T for attention PV: from QKV cols 5120..6143
  transpose_bf16<unsigned short><<<dim3(32, 128), 256, 0, stream>>>(QKVb + 5120, Vtg, 4096, 1024, 6144);

  // 1/sqrt(128) * log2(e) folded into Q (softmax uses exp2)
  const float qscale = 0.08838834764831845f * 1.44269504088896341f;
  rope_kernel<<<8192, 256, 0, stream>>>(QKVb, cosp, sinp, 6144, 5, S - 1, qscale, 4096 * 32 * 16);
  rope_kernel<<<2048, 256, 0, stream>>>(QKVb + 4096, cosp, sinp, 6144, 3, S - 1, 1.0f, 4096 * 8 * 16);

  attn_kernel<<<2048, 256, 0, stream>>>(QKVb, Vtg, AO, S, 4096);

  gemm_bt<false><<<1024, 256, 0, stream>>>(AO, Wot, d_out, 4096, 4096, 4096);
}

// Round 6
// 702.612 us; speedup vs baseline: 1.5853x; 1.2344x over previous
//
#include <hip/hip_runtime.h>

typedef __attribute__((ext_vector_type(8))) short short8;
typedef __attribute__((ext_vector_type(4))) float f32x4;
typedef __attribute__((ext_vector_type(4))) unsigned short u16x4;
typedef __attribute__((ext_vector_type(8))) unsigned short u16x8;

typedef __attribute__((address_space(3))) void lds_void;
typedef __attribute__((address_space(1))) void g_void;

#define GL16(g, l) __builtin_amdgcn_global_load_lds((g_void*)(g), (lds_void*)(l), 16, 0, 0)
#define EXP2F(x) __builtin_exp2f(x)

__device__ inline float b2f(unsigned short u) {
  union { unsigned u; float f; } v; v.u = ((unsigned)u) << 16; return v.f;
}
__device__ inline unsigned short f2b(float f) {
  union { float f; unsigned u; } v; v.f = f;
  unsigned r = v.u + 0x7FFFu + ((v.u >> 16) & 1u);
  return (unsigned short)(r >> 16);
}
// single-instruction RNE f32->bf16 (low half of packed convert)
__device__ inline unsigned short f2b_rne(float f) {
  unsigned u;
  asm("v_cvt_pk_bf16_f32 %0, %1, %2" : "=v"(u) : "v"(f), "v"(f));
  return (unsigned short)u;
}
__device__ inline unsigned short cvtb(float v) { return f2b(v); }
__device__ inline unsigned short cvtb(unsigned short v) { return v; }

// ---------- fp32 -> bf16 convert (vectorized) ----------
__global__ __launch_bounds__(256) void conv_f32_bf16(const float* __restrict__ in,
                                                     unsigned short* __restrict__ out, long n) {
  long i = ((long)blockIdx.x * 256 + threadIdx.x) * 4;
  if (i >= n) return;
  f32x4 v = *(const f32x4*)(in + i);
  u16x4 o;
  o[0] = f2b(v[0]); o[1] = f2b(v[1]); o[2] = f2b(v[2]); o[3] = f2b(v[3]);
  *(u16x4*)(out + i) = o;
}

// ---------- transpose (R x C block of ldin-stride matrix) -> bf16 (C x R) ----------
template <typename TIN>
__global__ __launch_bounds__(256) void transpose_bf16(const TIN* __restrict__ in,
                                                      unsigned short* __restrict__ out,
                                                      int R, int C, int ldin) {
  __shared__ unsigned short tile[32][33];
  int c0 = blockIdx.x * 32, r0 = blockIdx.y * 32;
  int tx = threadIdx.x & 31, ty = threadIdx.x >> 5;
#pragma unroll
  for (int i = ty; i < 32; i += 8)
    tile[i][tx] = cvtb(in[(long)(r0 + i) * ldin + c0 + tx]);
  __syncthreads();
#pragma unroll
  for (int i = ty; i < 32; i += 8)
    out[(long)(c0 + i) * R + r0 + tx] = tile[tx][i];
}

// ---------- RoPE in-place on bf16 (rows of ld elems, H heads x 128), scale folded ----------
__global__ __launch_bounds__(256) void rope_kernel(unsigned short* __restrict__ QK,
                                                   const float* __restrict__ cosp,
                                                   const float* __restrict__ sinp,
                                                   int ld, int hshift, int smask,
                                                   float scale, int total) {
  int idx = blockIdx.x * 256 + threadIdx.x;
  if (idx >= total) return;
  int seg = idx & 15;
  int hh = (idx >> 4) & ((1 << hshift) - 1);
  int row = idx >> (4 + hshift);
  int s = row & smask;
  int d0 = seg << 3;
  unsigned short* p = QK + (long)row * ld + hh * 128 + d0;
  u16x8 v = *(const u16x8*)p;
  u16x8 o;
  int ib = d0 >> 1;
#pragma unroll
  for (int q = 0; q < 4; q++) {
    float c = cosp[s * 64 + ib + q];
    float sn = sinp[s * 64 + ib + q];
    float e = b2f(v[2 * q]), od = b2f(v[2 * q + 1]);
    o[2 * q]     = f2b((e * c - od * sn) * scale);
    o[2 * q + 1] = f2b((e * sn + od * c) * scale);
  }
  *(u16x8*)p = o;
}

// ---------- bf16 GEMM: C(MxN) = A(MxK) * Bt(NxK)^T ; m97 structure ----------
template <bool OUT_BF16>
__global__ __launch_bounds__(256) void gemm_bt(const unsigned short* __restrict__ A,
                                               const unsigned short* __restrict__ Bt,
                                               void* __restrict__ C, int M, int N, int K) {
  __shared__ unsigned short As[128 * 32];
  __shared__ unsigned short Bs[128 * 32];
  const int tid = threadIdx.x;
  const int wave = tid >> 6, lane = tid & 63;
  const int lrow = lane & 15, kgrp = lane >> 4;
  const int nb = N >> 7;
  const int bm = blockIdx.x / nb, bn = blockIdx.x % nb;
  const int wr = wave >> 1, wc = wave & 1;

  f32x4 acc[4][4];
#pragma unroll
  for (int m = 0; m < 4; m++)
#pragma unroll
    for (int n = 0; n < 4; n++) acc[m][n] = (f32x4){0.f, 0.f, 0.f, 0.f};

  const char* ga = (const char*)(A + (long)(bm * 128 + (tid >> 2)) * K) + (tid & 3) * 16;
  const char* gb = (const char*)(Bt + (long)(bn * 128 + (tid >> 2)) * K) + (tid & 3) * 16;
  const long rowstep = (long)64 * K * 2;
  char* lA = (char*)As + wave * 1024;
  char* lB = (char*)Bs + wave * 1024;

  for (int k0 = 0; k0 < K; k0 += 32) {
    __syncthreads();
    GL16(ga + (long)k0 * 2, lA);
    GL16(ga + (long)k0 * 2 + rowstep, lA + 4096);
    GL16(gb + (long)k0 * 2, lB);
    GL16(gb + (long)k0 * 2 + rowstep, lB + 4096);
    __syncthreads();
    short8 af[4], bfv[4];
#pragma unroll
    for (int m = 0; m < 4; m++)
      af[m] = *(const short8*)(As + (wr * 64 + m * 16 + lrow) * 32 + kgrp * 8);
#pragma unroll
    for (int n = 0; n < 4; n++)
      bfv[n] = *(const short8*)(Bs + (wc * 64 + n * 16 + lrow) * 32 + kgrp * 8);
#pragma unroll
    for (int m = 0; m < 4; m++)
#pragma unroll
      for (int n = 0; n < 4; n++)
        acc[m][n] = __builtin_amdgcn_mfma_f32_16x16x32_bf16(af[m], bfv[n], acc[m][n], 0, 0, 0);
  }

  const long crow0 = (long)bm * 128 + wr * 64 + kgrp * 4;
  const int ccol0 = bn * 128 + wc * 64 + lrow;
#pragma unroll
  for (int m = 0; m < 4; m++)
#pragma unroll
    for (int n = 0; n < 4; n++)
#pragma unroll
      for (int r = 0; r < 4; r++) {
        long row = crow0 + m * 16 + r;
        int col = ccol0 + n * 16;
        if (OUT_BF16)
          ((unsigned short*)C)[row * N + col] = f2b(acc[m][n][r]);
        else
          ((float*)C)[row * N + col] = acc[m][n][r];
      }
}

// ---------- flash attention, causal, GQA(4:1), XOR-swizzled LDS ----------
// Work-balanced: each block handles q-tiles (qt, nqt-1-qt) -> uniform nqt+1 kv-tiles.
// QKV: (B*S) x 6144 bf16 (Q cols 0..4095 scale*log2e-folded, K cols 4096..5119),
// Vt: 1024 x (B*S) bf16 (transposed V), O: (B*S) x 4096 bf16
__global__ __launch_bounds__(256) void attn_kernel(const unsigned short* __restrict__ QKV,
                                                   const unsigned short* __restrict__ Vt,
                                                   unsigned short* __restrict__ O,
                                                   int S, int BS) {
  __shared__ unsigned short Ks[64 * 128];   // [kv][d], chunk^=(kv&7)
  __shared__ unsigned short Vs[128 * 64];   // [d][kv], chunk^=(d&7)
  __shared__ unsigned short Ps[4][16 * 68]; // per-wave [q][kv], pad 68
  const int tid = threadIdx.x, wave = tid >> 6, lane = tid & 63;
  const int lrow = lane & 15, kgrp = lane >> 4;
  const int nqt = S >> 6, nqt2 = nqt >> 1;
  int bid = blockIdx.x;
  const int qp = bid % nqt2; bid /= nqt2;
  const int h = bid & 31;
  const int b = bid >> 5;
  const int kh = h >> 2;
  const long rowbase = (long)b * S;

  // staging pointers (pass-invariant)
  const char* kg = (const char*)(QKV + rowbase * 6144 + 4096 + kh * 128)
                   + (tid >> 4) * 12288 + (((tid & 15) ^ ((tid >> 4) & 7)) * 16);
  const char* vg = (const char*)(Vt + (long)(kh * 128 + (tid >> 3)) * BS + rowbase)
                   + (((tid & 7) ^ ((tid >> 3) & 7)) * 16);
  char* lK = (char*)Ks + wave * 1024;
  char* lV = (char*)Vs + wave * 1024;

  for (int pass = 0; pass < 2; pass++) {
    const int qt = pass ? (nqt - 1 - qp) : qp;
    const int qbase = qt * 64;
    const int q0 = qbase + wave * 16;

    short8 qf[4];
    {
      const unsigned short* qpt = QKV + (rowbase + q0 + lrow) * 6144 + h * 128 + kgrp * 8;
#pragma unroll
      for (int dc = 0; dc < 4; dc++) qf[dc] = *(const short8*)(qpt + dc * 32);
    }
    f32x4 oacc[8];
#pragma unroll
    for (int dt = 0; dt < 8; dt++) oacc[dt] = (f32x4){0.f, 0.f, 0.f, 0.f};
    float mrun[4] = {-1e30f, -1e30f, -1e30f, -1e30f};
    float lrun[4] = {0.f, 0.f, 0.f, 0.f};

    const int kv_end = qbase + 64;
    for (int kv0 = 0; kv0 < kv_end; kv0 += 64) {
      __syncthreads();
#pragma unroll
      for (int p = 0; p < 4; p++)
        GL16(kg + (long)(kv0 + p * 16) * 12288, lK + p * 4096);
#pragma unroll
      for (int p = 0; p < 4; p++)
        GL16(vg + (long)kv0 * 2 + (long)p * 32 * BS * 2, lV + p * 4096);
      __syncthreads();

      f32x4 sc[4];
#pragma unroll
      for (int n = 0; n < 4; n++) {
        f32x4 s = (f32x4){0.f, 0.f, 0.f, 0.f};
#pragma unroll
        for (int dc = 0; dc < 4; dc++) {
          short8 kf = *(const short8*)(Ks + (n * 16 + lrow) * 128 + (((dc * 4 + kgrp) ^ (lrow & 7)) << 3));
          s = __builtin_amdgcn_mfma_f32_16x16x32_bf16(qf[dc], kf, s, 0, 0, 0);
        }
        sc[n] = s;
      }

      // diagonal tile only: causal mask
      if (kv0 + 63 > q0) {
#pragma unroll
        for (int r = 0; r < 4; r++) {
          const int qg = q0 + kgrp * 4 + r;
#pragma unroll
          for (int n = 0; n < 4; n++) {
            int kgi = kv0 + n * 16 + lrow;
            if (kgi > qg) sc[n][r] = -1e30f;
          }
        }
      }

      // per-row tile max
      float mx[4];
#pragma unroll
      for (int r = 0; r < 4; r++) {
        float m0 = fmaxf(fmaxf(sc[0][r], sc[1][r]), fmaxf(sc[2][r], sc[3][r]));
#pragma unroll
        for (int d = 1; d < 16; d <<= 1) m0 = fmaxf(m0, __shfl_xor(m0, d, 64));
        mx[r] = m0;
      }
      bool grow = false;
#pragma unroll
      for (int r = 0; r < 4; r++) grow = grow || (mx[r] > mrun[r] + 8.f);

      if (__all(!grow)) {
        // defer-rescale: keep old max, P bounded by 2^8
#pragma unroll
        for (int r = 0; r < 4; r++) {
          float psum = 0.f;
#pragma unroll
          for (int n = 0; n < 4; n++) {
            float pv = EXP2F(sc[n][r] - mrun[r]);
            psum += pv;
            Ps[wave][(kgrp * 4 + r) * 68 + n * 16 + lrow] = f2b_rne(pv);
          }
          lrun[r] += psum;
        }
      } else {
#pragma unroll
        for (int r = 0; r < 4; r++) {
          float mnew = fmaxf(mrun[r], mx[r]);
          float corr = EXP2F(mrun[r] - mnew);
          mrun[r] = mnew;
          float psum = 0.f;
#pragma unroll
          for (int n = 0; n < 4; n++) {
            float pv = EXP2F(sc[n][r] - mnew);
            psum += pv;
            Ps[wave][(kgrp * 4 + r) * 68 + n * 16 + lrow] = f2b_rne(pv);
          }
          lrun[r] = lrun[r] * corr + psum;
#pragma unroll
          for (int dt = 0; dt < 8; dt++) oacc[dt][r] *= corr;
        }
      }
      asm volatile("s_waitcnt lgkmcnt(0)" ::: "memory");
#pragma unroll
      for (int kc = 0; kc < 2; kc++) {
        short8 pa = *(const short8*)(&Ps[wave][lrow * 68 + kc * 32 + kgrp * 8]);
#pragma unroll
        for (int dt = 0; dt < 8; dt++) {
          short8 vb = *(const short8*)(Vs + (dt * 16 + lrow) * 64 + (((kc * 4 + kgrp) ^ (lrow & 7)) << 3));
          oacc[dt] = __builtin_amdgcn_mfma_f32_16x16x32_bf16(pa, vb, oacc[dt], 0, 0, 0);
        }
      }
    }

    float inv[4];
#pragma unroll
    for (int r = 0; r < 4; r++) {
      float l = lrun[r];
#pragma unroll
      for (int d = 1; d < 16; d <<= 1) l += __shfl_xor(l, d, 64);
      inv[r] = 1.f / l;
    }
    unsigned short* op = O + (rowbase + q0 + kgrp * 4) * 4096 + h * 128 + lrow;
#pragma unroll
    for (int dt = 0; dt < 8; dt++)
#pragma unroll
      for (int r = 0; r < 4; r++)
        op[(long)r * 4096 + dt * 16] = f2b_rne(oacc[dt][r] * inv[r]);
  }
}

extern "C" void kernel_launch(void* const* d_in, const int* in_sizes, int n_in,
                              void* d_out, int out_size, void* d_ws, size_t ws_size,
                              hipStream_t stream) {
  const float* x = (const float*)d_in[0];
  const float* cosp = (const float*)d_in[1];
  const float* sinp = (const float*)d_in[2];
  // d_in[3] = mask (causal 0/-1e9) -- applied analytically
  const float* Wq = (const float*)d_in[4];
  const float* Wk = (const float*)d_in[5];
  const float* Wv = (const float*)d_in[6];
  const float* Wo = (const float*)d_in[7];
  const int S = 2048;
  const long M = 4096; // B*S

  if (ws_size < 176160768ULL) return; // need 168 MiB scratch

  char* ws = (char*)d_ws;
  unsigned short* xb   = (unsigned short*)(ws);               // 32 MiB (aliased as AO later)
  unsigned short* Wqt  = (unsigned short*)(ws + 33554432);    // 32 MiB (Wqt,Wkt,Wvt contiguous: [6144][4096])
  unsigned short* Wkt  = (unsigned short*)(ws + 67108864);    //  8 MiB
  unsigned short* Wvt  = (unsigned short*)(ws + 75497472);    //  8 MiB
  unsigned short* Wot  = (unsigned short*)(ws + 83886080);    // 32 MiB
  unsigned short* QKVb = (unsigned short*)(ws + 117440512);   // 48 MiB [4096][6144]
  unsigned short* Vtg  = (unsigned short*)(ws + 167772160);   //  8 MiB [1024][4096]
  unsigned short* AO   = xb; // xb dead after QKV GEMM

  conv_f32_bf16<<<16384, 256, 0, stream>>>(x, xb, M * 4096);
  transpose_bf16<float><<<dim3(128, 128), 256, 0, stream>>>(Wq, Wqt, 4096, 4096, 4096);
  transpose_bf16<float><<<dim3(32, 128), 256, 0, stream>>>(Wk, Wkt, 4096, 1024, 1024);
  transpose_bf16<float><<<dim3(32, 128), 256, 0, stream>>>(Wv, Wvt, 4096, 1024, 1024);
  transpose_bf16<float><<<dim3(128, 128), 256, 0, stream>>>(Wo, Wot, 4096, 4096, 4096);

  // fused QKV projection: Bt = [Wqt|Wkt|Wvt] (6144 x 4096), C = QKVb (4096 x 6144)
  gemm_bt<true><<<1536, 256, 0, stream>>>(xb, Wqt, QKVb, 4096, 6144, 4096);
  // V^T for attention PV: from QKV cols 5120..6143
  transpose_bf16<unsigned short><<<dim3(32, 128), 256, 0, stream>>>(QKVb + 5120, Vtg, 4096, 1024, 6144);

  // 1/sqrt(128) * log2(e) folded into Q (softmax uses exp2)
  const float qscale = 0.08838834764831845f * 1.44269504088896341f;
  rope_kernel<<<8192, 256, 0, stream>>>(QKVb, cosp, sinp, 6144, 5, S - 1, qscale, 4096 * 32 * 16);
  rope_kernel<<<2048, 256, 0, stream>>>(QKVb + 4096, cosp, sinp, 6144, 3, S - 1, 1.0f, 4096 * 8 * 16);

  attn_kernel<<<1024, 256, 0, stream>>>(QKVb, Vtg, AO, S, 4096);

  gemm_bt<false><<<1024, 256, 0, stream>>>(AO, Wot, d_out, 4096, 4096, 4096);
}

// Round 7
// 631.731 us; speedup vs baseline: 1.7631x; 1.1122x over previous
//
#include <hip/hip_runtime.h>

typedef __attribute__((ext_vector_type(8))) short short8;
typedef __attribute__((ext_vector_type(4))) float f32x4;
typedef __attribute__((ext_vector_type(4))) unsigned short u16x4;
typedef __attribute__((ext_vector_type(8))) unsigned short u16x8;

typedef __attribute__((address_space(3))) void lds_void;
typedef __attribute__((address_space(1))) void g_void;

#define GL16(g, l) __builtin_amdgcn_global_load_lds((g_void*)(g), (lds_void*)(l), 16, 0, 0)
#define EXP2F(x) __builtin_exp2f(x)
#define BARRIER() do { asm volatile("" ::: "memory"); __builtin_amdgcn_s_barrier(); asm volatile("" ::: "memory"); } while (0)

__device__ inline float b2f(unsigned short u) {
  union { unsigned u; float f; } v; v.u = ((unsigned)u) << 16; return v.f;
}
__device__ inline unsigned short f2b(float f) {
  union { float f; unsigned u; } v; v.f = f;
  unsigned r = v.u + 0x7FFFu + ((v.u >> 16) & 1u);
  return (unsigned short)(r >> 16);
}
// single-instruction RNE f32->bf16 (low half of packed convert)
__device__ inline unsigned short f2b_rne(float f) {
  unsigned u;
  asm("v_cvt_pk_bf16_f32 %0, %1, %2" : "=v"(u) : "v"(f), "v"(f));
  return (unsigned short)u;
}
__device__ inline unsigned short cvtb(float v) { return f2b(v); }
__device__ inline unsigned short cvtb(unsigned short v) { return v; }

// ---------- fp32 -> bf16 convert (vectorized) ----------
__global__ __launch_bounds__(256) void conv_f32_bf16(const float* __restrict__ in,
                                                     unsigned short* __restrict__ out, long n) {
  long i = ((long)blockIdx.x * 256 + threadIdx.x) * 4;
  if (i >= n) return;
  f32x4 v = *(const f32x4*)(in + i);
  u16x4 o;
  o[0] = f2b(v[0]); o[1] = f2b(v[1]); o[2] = f2b(v[2]); o[3] = f2b(v[3]);
  *(u16x4*)(out + i) = o;
}

// ---------- transpose (R x C block of ldin-stride matrix) -> bf16 (C x R) ----------
template <typename TIN>
__global__ __launch_bounds__(256) void transpose_bf16(const TIN* __restrict__ in,
                                                      unsigned short* __restrict__ out,
                                                      int R, int C, int ldin) {
  __shared__ unsigned short tile[32][33];
  int c0 = blockIdx.x * 32, r0 = blockIdx.y * 32;
  int tx = threadIdx.x & 31, ty = threadIdx.x >> 5;
#pragma unroll
  for (int i = ty; i < 32; i += 8)
    tile[i][tx] = cvtb(in[(long)(r0 + i) * ldin + c0 + tx]);
  __syncthreads();
#pragma unroll
  for (int i = ty; i < 32; i += 8)
    out[(long)(c0 + i) * R + r0 + tx] = tile[tx][i];
}

// ---------- RoPE in-place on bf16 (rows of ld elems, H heads x 128), scale folded ----------
__global__ __launch_bounds__(256) void rope_kernel(unsigned short* __restrict__ QK,
                                                   const float* __restrict__ cosp,
                                                   const float* __restrict__ sinp,
                                                   int ld, int hshift, int smask,
                                                   float scale, int total) {
  int idx = blockIdx.x * 256 + threadIdx.x;
  if (idx >= total) return;
  int seg = idx & 15;
  int hh = (idx >> 4) & ((1 << hshift) - 1);
  int row = idx >> (4 + hshift);
  int s = row & smask;
  int d0 = seg << 3;
  unsigned short* p = QK + (long)row * ld + hh * 128 + d0;
  u16x8 v = *(const u16x8*)p;
  u16x8 o;
  int ib = d0 >> 1;
#pragma unroll
  for (int q = 0; q < 4; q++) {
    float c = cosp[s * 64 + ib + q];
    float sn = sinp[s * 64 + ib + q];
    float e = b2f(v[2 * q]), od = b2f(v[2 * q + 1]);
    o[2 * q]     = f2b((e * c - od * sn) * scale);
    o[2 * q + 1] = f2b((e * sn + od * c) * scale);
  }
  *(u16x8*)p = o;
}

// ---------- bf16 GEMM, 256x256 tile, BK=64, 8 waves, 4-phase pipelined ----------
// C(MxN) = A(MxK) * Bt(NxK)^T. LDS XOR-swizzled (chunk ^= row&7), double-buffered.
// A(t+1) staged in phase 0; B(t+2) staged in phase 1 (B-buffer freed after phase 0);
// per-tile gate = s_waitcnt vmcnt(4) -> B(t+2)'s loads stay in flight across the gate.
template <bool OUT_BF16>
__global__ __launch_bounds__(512, 2) void gemm_bt8(const unsigned short* __restrict__ A,
                                                   const unsigned short* __restrict__ Bt,
                                                   void* __restrict__ C, int M, int N, int K) {
  __shared__ unsigned short As[2 * 16384]; // 2 bufs x [256 rows][64 k] (swizzled 16B chunks)
  __shared__ unsigned short Bs[2 * 16384];
  const int tid = threadIdx.x;
  const int wid = tid >> 6, lane = tid & 63;
  const int lrow = lane & 15, kq = lane >> 4;
  const int wr = wid >> 2, wc = wid & 3; // 2M x 4N waves
  const int nbn = N >> 8;
  const int nwg = (M >> 8) * nbn;
  const int bid = blockIdx.x;
  const int cpx = nwg >> 3; // nwg % 8 == 0 for our shapes
  const int swz = (bid & 7) * cpx + (bid >> 3);
  const int bm = swz / nbn, bn = swz % nbn;

  const long K2 = (long)K * 2;
  // staging: thread -> (row = tid>>3 within 64-row segment, chunk = tid&7), source pre-swizzled
  const long csw = (long)(((tid & 7) ^ ((tid >> 3) & 7)) << 4);
  const char* gA = (const char*)A + ((long)bm * 256 + (tid >> 3)) * K2 + csw;
  const char* gB = (const char*)Bt + ((long)bn * 256 + (tid >> 3)) * K2 + csw;

#define STAGE4(gbase, lbase) do { \
    GL16((gbase),            (lbase)); \
    GL16((gbase) + 64 * K2,  (char*)(lbase) + 8192); \
    GL16((gbase) + 128 * K2, (char*)(lbase) + 16384); \
    GL16((gbase) + 192 * K2, (char*)(lbase) + 24576); } while (0)

  f32x4 acc[8][4];
#pragma unroll
  for (int mf = 0; mf < 8; mf++)
#pragma unroll
    for (int nf = 0; nf < 4; nf++) acc[mf][nf] = (f32x4){0.f, 0.f, 0.f, 0.f};

  const int arow = (wr * 128 + lrow) * 64;
  const int brow = (wc * 64 + lrow) * 64;
  const int ax = lrow & 7;

  // prologue: A(0)->As0, B(0)->Bs0, B(1)->Bs1
  STAGE4(gA, (char*)As + wid * 1024);
  STAGE4(gB, (char*)Bs + wid * 1024);
  STAGE4(gB + 128, (char*)Bs + 32768 + wid * 1024);
  asm volatile("s_waitcnt vmcnt(0)" ::: "memory");
  BARRIER();

  const int NT = K >> 6;
  for (int t = 0; t < NT; ++t) {
    const int c = t & 1;
    const unsigned short* Ab = As + c * 16384;
    const unsigned short* Bb = Bs + c * 16384;
    const long koff = (long)t << 7; // t*64 elems in bytes

    short8 bf[4][2], af[2][2];
    // ---- phase 0: B-frags (held all tile) + A mf0-1; stage A(t+1) ----
#pragma unroll
    for (int nf = 0; nf < 4; nf++)
#pragma unroll
      for (int kk = 0; kk < 2; kk++)
        bf[nf][kk] = *(const short8*)&Bb[brow + nf * 1024 + (((kk * 4 + kq) ^ ax) << 3)];
#pragma unroll
    for (int mf = 0; mf < 2; mf++)
#pragma unroll
      for (int kk = 0; kk < 2; kk++)
        af[mf][kk] = *(const short8*)&Ab[arow + mf * 1024 + (((kk * 4 + kq) ^ ax) << 3)];
    if (t + 1 < NT) STAGE4(gA + koff + 128, (char*)As + (c ^ 1) * 32768 + wid * 1024);
    BARRIER();
    __builtin_amdgcn_s_setprio(1);
#pragma unroll
    for (int mf = 0; mf < 2; mf++)
#pragma unroll
      for (int nf = 0; nf < 4; nf++)
#pragma unroll
        for (int kk = 0; kk < 2; kk++)
          acc[mf][nf] = __builtin_amdgcn_mfma_f32_16x16x32_bf16(af[mf][kk], bf[nf][kk], acc[mf][nf], 0, 0, 0);
    __builtin_amdgcn_s_setprio(0);
    BARRIER();

    // ---- phases 1-3: A mf 2-3 / 4-5 / 6-7; phase 1 stages B(t+2) into freed Bs[c] ----
#pragma unroll
    for (int ph = 1; ph < 4; ph++) {
      const int mb = ph * 2;
      short8 af2[2][2];
#pragma unroll
      for (int mf = 0; mf < 2; mf++)
#pragma unroll
        for (int kk = 0; kk < 2; kk++)
          af2[mf][kk] = *(const short8*)&Ab[arow + (mb + mf) * 1024 + (((kk * 4 + kq) ^ ax) << 3)];
      if (ph == 1 && t + 2 < NT) STAGE4(gB + koff + 256, (char*)Bs + c * 32768 + wid * 1024);
      BARRIER();
      __builtin_amdgcn_s_setprio(1);
#pragma unroll
      for (int mf = 0; mf < 2; mf++)
#pragma unroll
        for (int nf = 0; nf < 4; nf++)
#pragma unroll
          for (int kk = 0; kk < 2; kk++)
            acc[mb + mf][nf] = __builtin_amdgcn_mfma_f32_16x16x32_bf16(af2[mf][kk], bf[nf][kk], acc[mb + mf][nf], 0, 0, 0);
      __builtin_amdgcn_s_setprio(0);
      BARRIER();
    }

    // ---- gate: A(t+1)+B(t+1) landed; B(t+2) may stay in flight ----
    if (t + 2 < NT) {
      asm volatile("s_waitcnt vmcnt(4)" ::: "memory");
    } else if (t + 1 < NT) {
      asm volatile("s_waitcnt vmcnt(0)" ::: "memory");
    }
    BARRIER();
  }
#undef STAGE4

  const long crow0 = (long)bm * 256 + wr * 128 + kq * 4;
  const int ccol0 = bn * 256 + wc * 64 + lrow;
#pragma unroll
  for (int mf = 0; mf < 8; mf++)
#pragma unroll
    for (int nf = 0; nf < 4; nf++)
#pragma unroll
      for (int r = 0; r < 4; r++) {
        long row = crow0 + mf * 16 + r;
        int col = ccol0 + nf * 16;
        if (OUT_BF16)
          ((unsigned short*)C)[row * N + col] = f2b(acc[mf][nf][r]);
        else
          ((float*)C)[row * N + col] = acc[mf][nf][r];
      }
}

// ---------- flash attention, causal, GQA(4:1), XOR-swizzled LDS ----------
// Work-balanced: each block handles q-tiles (qt, nqt-1-qt) -> uniform nqt+1 kv-tiles.
__global__ __launch_bounds__(256) void attn_kernel(const unsigned short* __restrict__ QKV,
                                                   const unsigned short* __restrict__ Vt,
                                                   unsigned short* __restrict__ O,
                                                   int S, int BS) {
  __shared__ unsigned short Ks[64 * 128];   // [kv][d], chunk^=(kv&7)
  __shared__ unsigned short Vs[128 * 64];   // [d][kv], chunk^=(d&7)
  __shared__ unsigned short Ps[4][16 * 68]; // per-wave [q][kv], pad 68
  const int tid = threadIdx.x, wave = tid >> 6, lane = tid & 63;
  const int lrow = lane & 15, kgrp = lane >> 4;
  const int nqt = S >> 6, nqt2 = nqt >> 1;
  int bid = blockIdx.x;
  const int qp = bid % nqt2; bid /= nqt2;
  const int h = bid & 31;
  const int b = bid >> 5;
  const int kh = h >> 2;
  const long rowbase = (long)b * S;

  const char* kg = (const char*)(QKV + rowbase * 6144 + 4096 + kh * 128)
                   + (tid >> 4) * 12288 + (((tid & 15) ^ ((tid >> 4) & 7)) * 16);
  const char* vg = (const char*)(Vt + (long)(kh * 128 + (tid >> 3)) * BS + rowbase)
                   + (((tid & 7) ^ ((tid >> 3) & 7)) * 16);
  char* lK = (char*)Ks + wave * 1024;
  char* lV = (char*)Vs + wave * 1024;

  for (int pass = 0; pass < 2; pass++) {
    const int qt = pass ? (nqt - 1 - qp) : qp;
    const int qbase = qt * 64;
    const int q0 = qbase + wave * 16;

    short8 qf[4];
    {
      const unsigned short* qpt = QKV + (rowbase + q0 + lrow) * 6144 + h * 128 + kgrp * 8;
#pragma unroll
      for (int dc = 0; dc < 4; dc++) qf[dc] = *(const short8*)(qpt + dc * 32);
    }
    f32x4 oacc[8];
#pragma unroll
    for (int dt = 0; dt < 8; dt++) oacc[dt] = (f32x4){0.f, 0.f, 0.f, 0.f};
    float mrun[4] = {-1e30f, -1e30f, -1e30f, -1e30f};
    float lrun[4] = {0.f, 0.f, 0.f, 0.f};

    const int kv_end = qbase + 64;
    for (int kv0 = 0; kv0 < kv_end; kv0 += 64) {
      __syncthreads();
#pragma unroll
      for (int p = 0; p < 4; p++)
        GL16(kg + (long)(kv0 + p * 16) * 12288, lK + p * 4096);
#pragma unroll
      for (int p = 0; p < 4; p++)
        GL16(vg + (long)kv0 * 2 + (long)p * 32 * BS * 2, lV + p * 4096);
      __syncthreads();

      f32x4 sc[4];
#pragma unroll
      for (int n = 0; n < 4; n++) {
        f32x4 s = (f32x4){0.f, 0.f, 0.f, 0.f};
#pragma unroll
        for (int dc = 0; dc < 4; dc++) {
          short8 kf = *(const short8*)(Ks + (n * 16 + lrow) * 128 + (((dc * 4 + kgrp) ^ (lrow & 7)) << 3));
          s = __builtin_amdgcn_mfma_f32_16x16x32_bf16(qf[dc], kf, s, 0, 0, 0);
        }
        sc[n] = s;
      }

      if (kv0 + 63 > q0) {
#pragma unroll
        for (int r = 0; r < 4; r++) {
          const int qg = q0 + kgrp * 4 + r;
#pragma unroll
          for (int n = 0; n < 4; n++) {
            int kgi = kv0 + n * 16 + lrow;
            if (kgi > qg) sc[n][r] = -1e30f;
          }
        }
      }

      float mx[4];
#pragma unroll
      for (int r = 0; r < 4; r++) {
        float m0 = fmaxf(fmaxf(sc[0][r], sc[1][r]), fmaxf(sc[2][r], sc[3][r]));
#pragma unroll
        for (int d = 1; d < 16; d <<= 1) m0 = fmaxf(m0, __shfl_xor(m0, d, 64));
        mx[r] = m0;
      }
      bool grow = false;
#pragma unroll
      for (int r = 0; r < 4; r++) grow = grow || (mx[r] > mrun[r] + 8.f);

      if (__all(!grow)) {
#pragma unroll
        for (int r = 0; r < 4; r++) {
          float psum = 0.f;
#pragma unroll
          for (int n = 0; n < 4; n++) {
            float pv = EXP2F(sc[n][r] - mrun[r]);
            psum += pv;
            Ps[wave][(kgrp * 4 + r) * 68 + n * 16 + lrow] = f2b_rne(pv);
          }
          lrun[r] += psum;
        }
      } else {
#pragma unroll
        for (int r = 0; r < 4; r++) {
          float mnew = fmaxf(mrun[r], mx[r]);
          float corr = EXP2F(mrun[r] - mnew);
          mrun[r] = mnew;
          float psum = 0.f;
#pragma unroll
          for (int n = 0; n < 4; n++) {
            float pv = EXP2F(sc[n][r] - mnew);
            psum += pv;
            Ps[wave][(kgrp * 4 + r) * 68 + n * 16 + lrow] = f2b_rne(pv);
          }
          lrun[r] = lrun[r] * corr + psum;
#pragma unroll
          for (int dt = 0; dt < 8; dt++) oacc[dt][r] *= corr;
        }
      }
      asm volatile("s_waitcnt lgkmcnt(0)" ::: "memory");
#pragma unroll
      for (int kc = 0; kc < 2; kc++) {
        short8 pa = *(const short8*)(&Ps[wave][lrow * 68 + kc * 32 + kgrp * 8]);
#pragma unroll
        for (int dt = 0; dt < 8; dt++) {
          short8 vb = *(const short8*)(Vs + (dt * 16 + lrow) * 64 + (((kc * 4 + kgrp) ^ (lrow & 7)) << 3));
          oacc[dt] = __builtin_amdgcn_mfma_f32_16x16x32_bf16(pa, vb, oacc[dt], 0, 0, 0);
        }
      }
    }

    float inv[4];
#pragma unroll
    for (int r = 0; r < 4; r++) {
      float l = lrun[r];
#pragma unroll
      for (int d = 1; d < 16; d <<= 1) l += __shfl_xor(l, d, 64);
      inv[r] = 1.f / l;
    }
    unsigned short* op = O + (rowbase + q0 + kgrp * 4) * 4096 + h * 128 + lrow;
#pragma unroll
    for (int dt = 0; dt < 8; dt++)
#pragma unroll
      for (int r = 0; r < 4; r++)
        op[(long)r * 4096 + dt * 16] = f2b_rne(oacc[dt][r] * inv[r]);
  }
}

extern "C" void kernel_launch(void* const* d_in, const int* in_sizes, int n_in,
                              void* d_out, int out_size, void* d_ws, size_t ws_size,
                              hipStream_t stream) {
  const float* x = (const float*)d_in[0];
  const float* cosp = (const float*)d_in[1];
  const float* sinp = (const float*)d_in[2];
  // d_in[3] = mask (causal 0/-1e9) -- applied analytically
  const float* Wq = (const float*)d_in[4];
  const float* Wk = (const float*)d_in[5];
  const float* Wv = (const float*)d_in[6];
  const float* Wo = (const float*)d_in[7];
  const int S = 2048;
  const long M = 4096; // B*S

  if (ws_size < 176160768ULL) return; // need 168 MiB scratch

  char* ws = (char*)d_ws;
  unsigned short* xb   = (unsigned short*)(ws);               // 32 MiB (aliased as AO later)
  unsigned short* Wqt  = (unsigned short*)(ws + 33554432);    // 32 MiB (Wqt,Wkt,Wvt contiguous: [6144][4096])
  unsigned short* Wkt  = (unsigned short*)(ws + 67108864);    //  8 MiB
  unsigned short* Wvt  = (unsigned short*)(ws + 75497472);    //  8 MiB
  unsigned short* Wot  = (unsigned short*)(ws + 83886080);    // 32 MiB
  unsigned short* QKVb = (unsigned short*)(ws + 117440512);   // 48 MiB [4096][6144]
  unsigned short* Vtg  = (unsigned short*)(ws + 167772160);   //  8 MiB [1024][4096]
  unsigned short* AO   = xb; // xb dead after QKV GEMM

  conv_f32_bf16<<<16384, 256, 0, stream>>>(x, xb, M * 4096);
  transpose_bf16<float><<<dim3(128, 128), 256, 0, stream>>>(Wq, Wqt, 4096, 4096, 4096);
  transpose_bf16<float><<<dim3(32, 128), 256, 0, stream>>>(Wk, Wkt, 4096, 1024, 1024);
  transpose_bf16<float><<<dim3(32, 128), 256, 0, stream>>>(Wv, Wvt, 4096, 1024, 1024);
  transpose_bf16<float><<<dim3(128, 128), 256, 0, stream>>>(Wo, Wot, 4096, 4096, 4096);

  // fused QKV projection: Bt = [Wqt|Wkt|Wvt] (6144 x 4096), C = QKVb (4096 x 6144)
  gemm_bt8<true><<<384, 512, 0, stream>>>(xb, Wqt, QKVb, 4096, 6144, 4096);
  // V^T for attention PV: from QKV cols 5120..6143
  transpose_bf16<unsigned short><<<dim3(32, 128), 256, 0, stream>>>(QKVb + 5120, Vtg, 4096, 1024, 6144);

  // 1/sqrt(128) * log2(e) folded into Q (softmax uses exp2)
  const float qscale = 0.08838834764831845f * 1.44269504088896341f;
  rope_kernel<<<8192, 256, 0, stream>>>(QKVb, cosp, sinp, 6144, 5, S - 1, qscale, 4096 * 32 * 16);
  rope_kernel<<<2048, 256, 0, stream>>>(QKVb + 4096, cosp, sinp, 6144, 3, S - 1, 1.0f, 4096 * 8 * 16);

  attn_kernel<<<1024, 256, 0, stream>>>(QKVb, Vtg, AO, S, 4096);

  gemm_bt8<false><<<256, 512, 0, stream>>>(AO, Wot, d_out, 4096, 4096, 4096);
}